// Round 9
// baseline (254.379 us; speedup 1.0000x reference)
//
#include <hip/hip_runtime.h>

// ---------------------------------------------------------------------------
// TransNetSweepingExplRhs — analytic reduction (derivation in R1/R2):
//   h = x@W_in^T + b_in ; th = tanh(h); r1u = h + 0.1 b1
//   Q_i = I/11 - (0.01/121) W_i^T W_i      (1-term Neumann inverse)
//   b1v = 11 th + 0.1 (r1u@W1); y1v = b1v@Q1
//   r2u = r1u - 0.1 (y1v@W1^T) + 0.1 b2
//   b2v = 10 th + y1v + 0.1 (r2u@W2); y2v = b2v@Q2
//   y2u = r2u - 0.1 (y2v@W2^T);  out = softmax(y2u@W_out^T + b_out)
// R9: single FUSED kernel (512 blocks = 2/CU co-resident, R6 geometry) with
// per-bx-group flag pipelining. All chain deps are row-local (A rows bx);
// B operands are weights/Q. Inter-stage tensors written via AGENT-scope
// atomic exchange (LLC-coherent regardless of XCD mapping — G16-safe);
// flags: vmcnt(0) + relaxed add; consumer finite-spin + acquire.
// K-loop = R6's proven gload_lds 3-buffer counted-vmcnt pipeline (untouched).
// Kills ~7 dispatch boundaries (~30 us) + overlaps stages across bx groups.
// ---------------------------------------------------------------------------

typedef short bf16x8 __attribute__((ext_vector_type(8)));
typedef float f32x4 __attribute__((ext_vector_type(4)));

#define M1 1048576

__device__ __forceinline__ unsigned short f2b(float f) {
  union { float f; unsigned int u; } v; v.f = f;
  unsigned int u = v.u;
  return (unsigned short)((u + 0x7FFFu + ((u >> 16) & 1u)) >> 16);
}

__device__ __forceinline__ void gload16(const void* g, void* l) {
  __builtin_amdgcn_global_load_lds(
      (const __attribute__((address_space(1))) unsigned int*)g,
      (__attribute__((address_space(3))) unsigned int*)l, 16, 0, 0);
}

__device__ __forceinline__ void atomf(float* p, float v) {
  (void)__hip_atomic_exchange(p, v, __ATOMIC_RELAXED, __HIP_MEMORY_SCOPE_AGENT);
}
__device__ __forceinline__ void atomu(unsigned* p, unsigned v) {
  (void)__hip_atomic_exchange(p, v, __ATOMIC_RELAXED, __HIP_MEMORY_SCOPE_AGENT);
}

// producer: drain stores, block-sync, one atomicAdd
__device__ __forceinline__ void signal(unsigned* c) {
  asm volatile("s_waitcnt vmcnt(0)" ::: "memory");
  __syncthreads();
  if (threadIdx.x == 0)
    (void)__hip_atomic_fetch_add(c, 1u, __ATOMIC_RELAXED, __HIP_MEMORY_SCOPE_AGENT);
}

// consumer: finite spin (deadlock -> wrong result, not hang), acquire, sync
__device__ __forceinline__ void waitflag(unsigned* c, unsigned tgt) {
  if (threadIdx.x == 0) {
    for (int it = 0; it < 6000000; ++it) {
      if (__hip_atomic_load(c, __ATOMIC_RELAXED, __HIP_MEMORY_SCOPE_AGENT) >= tgt) break;
      __builtin_amdgcn_s_sleep(2);
    }
    (void)__hip_atomic_load(c, __ATOMIC_ACQUIRE, __HIP_MEMORY_SCOPE_AGENT);
  }
  __syncthreads();
}

struct FP {
  const float *x, *W_in, *b_in, *W1, *b1, *W2, *b2, *W_out, *b_out;
  float* out;
  unsigned short *xb, *winb, *wb, *wtb, *qb, *woutb;
  unsigned short *zb0, *zb1, *zb2, *zb3, *zb4, *zb5, *zb6;
  float *boutp, *r1u, *th, *y1v, *r2u, *lgts;
  unsigned* flg;  // flg[s*32+bx] s=0..7 ; flg[256]=QG count
};

// C[m,n] = sum_k A[m,k]*B[n,k], K=1024, tile 64x64 at (bx,by), BK=64.
// R6 core: 4 waves (2x2, wave tile 32x32), 3-buffer depth-2 counted-vmcnt
// pipeline, 8-chunk rotation swizzle (pre-swizzled gload source + swizzled
// ds_read). Epilogue stores via agent-scope atomics (bf16 lane-pair packed).
template <int MODE>
__device__ __forceinline__ void gemm64(
    const unsigned short* __restrict__ A, const unsigned short* __restrict__ B,
    int bx, int by,
    const float* bias0, const float* bias1,
    const float* src0, const float* src1,
    float* dstf0, float* dstf1, unsigned short* dstbf,
    short (*As)[4096], short (*Bs)[4096]) {
  const int tid = threadIdx.x;
  const int lane = tid & 63;
  const int wid = tid >> 6;
  const int wr = wid >> 1;
  const int wc = wid & 1;
  const int m0 = bx * 64;
  const int n0 = by * 64;
  const int l15 = lane & 15;
  const int kb = lane >> 4;

  const int sr = tid >> 3;
  const int sg = ((tid & 7) - sr) & 7;
  const unsigned short* Asrc = A + (size_t)(m0 + sr) * 1024 + sg * 8;
  const unsigned short* Bsrc = B + (size_t)(n0 + sr) * 1024 + sg * 8;
  const int o0 = tid * 8;
  const int o1 = 2048 + tid * 8;

  f32x4 acc[2][2];
#pragma unroll
  for (int f = 0; f < 2; ++f)
#pragma unroll
    for (int g = 0; g < 2; ++g) acc[f][g] = (f32x4){0.f, 0.f, 0.f, 0.f};

#define STG9(kt, buf)                                        \
  do {                                                       \
    gload16(Asrc + (kt) * 64, &As[(buf)][o0]);               \
    gload16(Asrc + 32 * 1024 + (kt) * 64, &As[(buf)][o1]);   \
    gload16(Bsrc + (kt) * 64, &Bs[(buf)][o0]);               \
    gload16(Bsrc + 32 * 1024 + (kt) * 64, &Bs[(buf)][o1]);   \
  } while (0)

  STG9(0, 0);
  STG9(1, 1);

#pragma unroll
  for (int t = 0; t < 16; ++t) {
    if (t < 15) {
      asm volatile("s_waitcnt vmcnt(4)" ::: "memory");
    } else {
      asm volatile("s_waitcnt vmcnt(0)" ::: "memory");
    }
    __builtin_amdgcn_sched_barrier(0);
    __builtin_amdgcn_s_barrier();
    __builtin_amdgcn_sched_barrier(0);
    if (t + 2 < 16) STG9(t + 2, (t + 2) % 3);
    const int cb = t % 3;
    bf16x8 av[2][2], bv[2][2];
#pragma unroll
    for (int f = 0; f < 2; ++f) {
      const int ra = wr * 32 + f * 16 + l15;
#pragma unroll
      for (int ks = 0; ks < 2; ++ks) {
        const int qa = (ks * 4 + kb + l15) & 7;
        av[f][ks] = *reinterpret_cast<const bf16x8*>(&As[cb][ra * 64 + qa * 8]);
      }
    }
#pragma unroll
    for (int g = 0; g < 2; ++g) {
      const int rb = wc * 32 + g * 16 + l15;
#pragma unroll
      for (int ks = 0; ks < 2; ++ks) {
        const int qb2 = (ks * 4 + kb + l15) & 7;
        bv[g][ks] = *reinterpret_cast<const bf16x8*>(&Bs[cb][rb * 64 + qb2 * 8]);
      }
    }
#pragma unroll
    for (int ks = 0; ks < 2; ++ks)
#pragma unroll
      for (int f = 0; f < 2; ++f)
#pragma unroll
        for (int g = 0; g < 2; ++g)
          acc[f][g] = __builtin_amdgcn_mfma_f32_16x16x32_bf16(av[f][ks], bv[g][ks], acc[f][g], 0, 0, 0);
  }
#undef STG9

  // epilogue: C/D col = lane&15, row = (lane>>4)*4 + j
#pragma unroll
  for (int f = 0; f < 2; ++f) {
#pragma unroll
    for (int g = 0; g < 2; ++g) {
#pragma unroll
      for (int j = 0; j < 4; ++j) {
        int m = m0 + wr * 32 + f * 16 + kb * 4 + j;
        int n = n0 + wc * 32 + g * 16 + l15;
        size_t idx = (size_t)m * 1024 + n;
        float v = acc[f][g][j];
        float bfv = 0.0f;
        if (MODE == 0) {
          bfv = v;
        } else if (MODE == 1) {
          float h = v + bias0[n];
          float thv = tanhf(h);
          float r = h + 0.1f * bias1[n];
          atomf(dstf0 + idx, r);
          atomf(dstf1 + idx, thv);
          bfv = r;
        } else if (MODE == 2) {
          bfv = 11.0f * src0[idx] + 0.1f * v;
        } else if (MODE == 3) {
          atomf(dstf0 + idx, v);
          bfv = v;
        } else if (MODE == 4) {
          float r = src0[idx] - 0.1f * v + 0.1f * bias0[n];
          atomf(dstf0 + idx, r);
          bfv = r;
        } else if (MODE == 5) {
          bfv = 10.0f * src0[idx] + src1[idx] + 0.1f * v;
        } else if (MODE == 7) {
          bfv = src0[idx] - 0.1f * v;
        } else if (MODE == 8) {
          atomf(dstf0 + idx, v + bias0[n]);
        } else {  // MODE 9
          bfv = (m == n ? (1.0f / 11.0f) : 0.0f) - (0.01f / 121.0f) * v;
        }
        if (MODE != 8) {
          unsigned mb = (unsigned)f2b(bfv);
          unsigned pr = (unsigned)__shfl_xor((int)mb, 1);
          if (!(lane & 1))
            atomu((unsigned*)dstbf + (idx >> 1), mb | (pr << 16));
        }
      }
    }
  }
}

__global__ __launch_bounds__(256) void fused(FP p) {
  __shared__ short As[3][4096];
  __shared__ short Bs[3][4096];
  __shared__ float redm[4];
  __shared__ float reds[4];
  const int b = blockIdx.x;
  const int tid = threadIdx.x;
  const int bx = ((b & 7) << 2) | ((b >> 3) & 3);  // 0..31
  const int by = b >> 5;                           // 0..15
  unsigned* flg = p.flg;

  // stage 0a: G0 (h-stage) -> r1u, th, zb0
  gemm64<1>(p.xb, p.winb, bx, by, p.b_in, p.b1, nullptr, nullptr,
            p.r1u, p.th, p.zb0, As, Bs);
  signal(&flg[0 * 32 + bx]);
  // stage 0b: QG tile (Q1,Q2)
  {
    const int z = b >> 8;
    const int r = b & 255;
    const int qbx = ((r & 7) << 1) | ((r >> 3) & 1);  // 0..15
    const int qby = (r >> 4) & 15;                    // 0..15
    const unsigned short* wt = p.wtb + (size_t)z * M1;
    gemm64<9>(wt, wt, qbx, qby, nullptr, nullptr, nullptr, nullptr,
              nullptr, nullptr, p.qb + (size_t)z * M1, As, Bs);
  }
  signal(&flg[256]);

  // G1: c1 = r1u@W1 -> b1v (zb1)
  waitflag(&flg[0 * 32 + bx], 16);
  gemm64<2>(p.zb0, p.wtb, bx, by, nullptr, nullptr, p.th, nullptr,
            nullptr, nullptr, p.zb1, As, Bs);
  signal(&flg[1 * 32 + bx]);

  // G2: y1v = b1v@Q1 (needs all QG tiles)
  waitflag(&flg[1 * 32 + bx], 16);
  waitflag(&flg[256], 512);
  gemm64<3>(p.zb1, p.qb, bx, by, nullptr, nullptr, nullptr, nullptr,
            p.y1v, nullptr, p.zb2, As, Bs);
  signal(&flg[2 * 32 + bx]);

  // G3: r2u = r1u - 0.1 (y1v@W1^T) + 0.1 b2
  waitflag(&flg[2 * 32 + bx], 16);
  gemm64<4>(p.zb2, p.wb, bx, by, p.b2, nullptr, p.r1u, nullptr,
            p.r2u, nullptr, p.zb3, As, Bs);
  signal(&flg[3 * 32 + bx]);

  // G4: b2v = 10 th + y1v + 0.1 (r2u@W2)
  waitflag(&flg[3 * 32 + bx], 16);
  gemm64<5>(p.zb3, p.wtb + M1, bx, by, nullptr, nullptr, p.th, p.y1v,
            nullptr, nullptr, p.zb4, As, Bs);
  signal(&flg[4 * 32 + bx]);

  // G5: y2v = b2v@Q2
  waitflag(&flg[4 * 32 + bx], 16);
  gemm64<0>(p.zb4, p.qb + M1, bx, by, nullptr, nullptr, nullptr, nullptr,
            nullptr, nullptr, p.zb5, As, Bs);
  signal(&flg[5 * 32 + bx]);

  // G6: y2u = r2u - 0.1 (y2v@W2^T)
  waitflag(&flg[5 * 32 + bx], 16);
  gemm64<7>(p.zb5, p.wb + M1, bx, by, nullptr, nullptr, p.r2u, nullptr,
            nullptr, nullptr, p.zb6, As, Bs);
  signal(&flg[6 * 32 + bx]);

  // G7: logits = y2u@Wout^T + bout
  waitflag(&flg[6 * 32 + bx], 16);
  gemm64<8>(p.zb6, p.woutb, bx, by, p.boutp, nullptr, nullptr, nullptr,
            p.lgts, nullptr, nullptr, As, Bs);
  signal(&flg[7 * 32 + bx]);

  // softmax: 4 rows (bx*64 + by*4 ..), needs this bx group's logits
  waitflag(&flg[7 * 32 + bx], 16);
  {
    const int lane = tid & 63;
    const int w = tid >> 6;
    for (int rr = 0; rr < 4; ++rr) {
      int row = bx * 64 + by * 4 + rr;
      const float* prow = p.lgts + (size_t)row * 1024;
      float* qrow = p.out + (size_t)row * 1000;
      float m = -3.0e38f;
      for (int i = tid; i < 1000; i += 256) m = fmaxf(m, prow[i]);
#pragma unroll
      for (int o = 32; o > 0; o >>= 1) m = fmaxf(m, __shfl_xor(m, o));
      if (lane == 0) redm[w] = m;
      __syncthreads();
      m = fmaxf(fmaxf(redm[0], redm[1]), fmaxf(redm[2], redm[3]));
      float s = 0.0f;
      for (int i = tid; i < 1000; i += 256) {
        float e = __expf(prow[i] - m);
        qrow[i] = e;
        s += e;
      }
#pragma unroll
      for (int o = 32; o > 0; o >>= 1) s += __shfl_xor(s, o);
      if (lane == 0) reds[w] = s;
      __syncthreads();
      float inv = 1.0f / (reds[0] + reds[1] + reds[2] + reds[3]);
      for (int i = tid; i < 1000; i += 256) qrow[i] *= inv;
      __syncthreads();
    }
  }
}

// one-dispatch prep (unchanged from R6): W1/W2 bf16+transpose, x, W_in,
// W_out padded, b_out padded
__global__ __launch_bounds__(256) void k_prep(
    const float* __restrict__ x, const float* __restrict__ Win,
    const float* __restrict__ W1, const float* __restrict__ W2,
    const float* __restrict__ Wout, const float* __restrict__ bout,
    unsigned short* __restrict__ xb, unsigned short* __restrict__ winb,
    unsigned short* __restrict__ wb, unsigned short* __restrict__ wtb,
    unsigned short* __restrict__ woutb, float* __restrict__ boutp) {
  __shared__ float tile[32][33];
  const int b = blockIdx.x;
  const int tid = threadIdx.x;
  if (b < 2048) {
    const float* W = (b & 1024) ? W2 : W1;
    unsigned short* Wb = wb + ((size_t)(b >> 10) << 20);
    unsigned short* WTb = wtb + ((size_t)(b >> 10) << 20);
    const int rem = b & 1023;
    const int tbx = rem & 31, tby = rem >> 5;
    const int tx = tid & 31, ty = tid >> 5;
#pragma unroll
    for (int i = ty; i < 32; i += 8) {
      float v = W[(size_t)(tby * 32 + i) * 1024 + tbx * 32 + tx];
      tile[i][tx] = v;
      Wb[(size_t)(tby * 32 + i) * 1024 + tbx * 32 + tx] = f2b(v);
    }
    __syncthreads();
#pragma unroll
    for (int i = ty; i < 32; i += 8)
      WTb[(size_t)(tbx * 32 + i) * 1024 + tby * 32 + tx] = f2b(tile[tx][i]);
  } else if (b < 4096) {
    int i = (b - 2048) * 256 + tid;
    float4 v = ((const float4*)x)[i];
    ((ushort4*)xb)[i] = (ushort4){f2b(v.x), f2b(v.y), f2b(v.z), f2b(v.w)};
  } else if (b < 5120) {
    int i = (b - 4096) * 256 + tid;
    float4 v = ((const float4*)Win)[i];
    ((ushort4*)winb)[i] = (ushort4){f2b(v.x), f2b(v.y), f2b(v.z), f2b(v.w)};
  } else if (b < 6144) {
    int i = (b - 5120) * 256 + tid;
    ushort4 o = (ushort4){0, 0, 0, 0};
    if ((i >> 8) < 1000) {
      float4 v = ((const float4*)Wout)[i];
      o = (ushort4){f2b(v.x), f2b(v.y), f2b(v.z), f2b(v.w)};
    }
    ((ushort4*)woutb)[i] = o;
  } else {
    for (int j = tid; j < 1024; j += 256) boutp[j] = (j < 1000) ? bout[j] : 0.0f;
  }
}

extern "C" void kernel_launch(void* const* d_in, const int* in_sizes, int n_in,
                              void* d_out, int out_size, void* d_ws, size_t ws_size,
                              hipStream_t stream) {
  const size_t Bm = 2048, U = 1024;
  char* ws = (char*)d_ws;
  size_t off = 0;
  auto alloc = [&](size_t bytes) -> void* {
    void* pp = ws + off;
    off += (bytes + 255) & ~(size_t)255;
    return pp;
  };

  FP p;
  p.x = (const float*)d_in[0];
  p.W_in = (const float*)d_in[1];
  p.b_in = (const float*)d_in[2];
  p.W1 = (const float*)d_in[3];
  p.b1 = (const float*)d_in[4];
  p.W2 = (const float*)d_in[5];
  p.b2 = (const float*)d_in[6];
  p.W_out = (const float*)d_in[7];
  p.b_out = (const float*)d_in[8];
  p.out = (float*)d_out;

  p.xb = (unsigned short*)alloc(Bm * U * 2);
  p.winb = (unsigned short*)alloc((size_t)M1 * 2);
  p.wb = (unsigned short*)alloc(2 * (size_t)M1 * 2);
  p.wtb = (unsigned short*)alloc(2 * (size_t)M1 * 2);
  p.qb = (unsigned short*)alloc(2 * (size_t)M1 * 2);
  p.woutb = (unsigned short*)alloc((size_t)M1 * 2);
  p.zb0 = (unsigned short*)alloc(Bm * U * 2);
  p.zb1 = (unsigned short*)alloc(Bm * U * 2);
  p.zb2 = (unsigned short*)alloc(Bm * U * 2);
  p.zb3 = (unsigned short*)alloc(Bm * U * 2);
  p.zb4 = (unsigned short*)alloc(Bm * U * 2);
  p.zb5 = (unsigned short*)alloc(Bm * U * 2);
  p.zb6 = (unsigned short*)alloc(Bm * U * 2);
  p.boutp = (float*)alloc(U * 4);
  p.r1u = (float*)alloc(Bm * U * 4);
  p.th = (float*)alloc(Bm * U * 4);
  p.y1v = (float*)alloc(Bm * U * 4);
  p.r2u = (float*)alloc(Bm * U * 4);
  p.lgts = (float*)alloc(Bm * U * 4);
  p.flg = (unsigned*)alloc(2048);

  hipMemsetAsync(p.flg, 0, 2048, stream);
  k_prep<<<6145, 256, 0, stream>>>(p.x, p.W_in, p.W1, p.W2, p.W_out, p.b_out,
                                   p.xb, p.winb, p.wb, p.wtb, p.woutb, p.boutp);
  fused<<<512, 256, 0, stream>>>(p);
}

// Round 10
// 111.545 us; speedup vs baseline: 2.2805x; 2.2805x over previous
//
#include <hip/hip_runtime.h>

// ---------------------------------------------------------------------------
// TransNetSweepingExplRhs — analytic reduction, restructured chain (R10):
//   h = x@W_in^T + b_in ; th = tanh(h); r1u = h + 0.1 b1
//   Q_i = I/11 - (0.01/121) W_i^T W_i   (symmetric);  A_i = W_i@Q_i
//   b1v = 11 th + 0.1 (r1u@W1)
//   r2u = r1u + 0.1 b2 - 0.1 (b1v@Q1W1^T)            [= NT(b1v, A1)]
//   b2v = 10 th + [b1v | 0.1 r2u] @ [Q1 ; W2]        [one K=2048 GEMM]
//   y2u = r2u - 0.1 (b2v@Q2W2^T)                     [= NT(b2v, A2)]
//   logits = y2u@W_out^T + b_out ; out = softmax
// Lessons: R7/R9 (in-kernel grid sync / atomics) are net losses; gaps are
// ~1-2us. Keep R6 multi-dispatch + proven 3-buffer counted-vmcnt K-loop;
// cut sequential batch GEMMs 8->6 and overlap weight GEMMs with the chain.
// ---------------------------------------------------------------------------

typedef short bf16x8 __attribute__((ext_vector_type(8)));
typedef float f32x4 __attribute__((ext_vector_type(4)));

#define M1 1048576

__device__ __forceinline__ unsigned short f2b(float f) {
  union { float f; unsigned int u; } v; v.f = f;
  unsigned int u = v.u;
  return (unsigned short)((u + 0x7FFFu + ((u >> 16) & 1u)) >> 16);
}

__device__ __forceinline__ void gload16(const void* g, void* l) {
  __builtin_amdgcn_global_load_lds(
      (const __attribute__((address_space(1))) unsigned int*)g,
      (__attribute__((address_space(3))) unsigned int*)l, 16, 0, 0);
}

// C[m,n] = sum_k A[m,k]*B[n,k]; tile 64x64 at (bx,by); K = NKT*64.
// R6 core: 4 waves (2x2, wave tile 32x32), BK=64, 3-buffer depth-2 pipeline,
// counted vmcnt(4) (vmcnt(0) only last phase), 8-chunk rotation swizzle
// (pre-swizzled gload source + swizzled ds_read). lda/ldb row strides.
template <int MODE, int NKT>
__device__ __forceinline__ void gemm64(
    const unsigned short* __restrict__ A, int lda,
    const unsigned short* __restrict__ B, int ldb,
    int bx, int by,
    const float* bias0, const float* bias1, const float* src0,
    float* dstf0, float* dstf1,
    unsigned short* dstbf, int ldc, unsigned short* dstbf2,
    short (*As)[4096], short (*Bs)[4096]) {
  const int tid = threadIdx.x;
  const int lane = tid & 63;
  const int wid = tid >> 6;
  const int wr = wid >> 1;
  const int wc = wid & 1;
  const int m0 = bx * 64;
  const int n0 = by * 64;
  const int l15 = lane & 15;
  const int kb = lane >> 4;

  const int sr = tid >> 3;
  const int sg = ((tid & 7) - sr) & 7;
  const unsigned short* Asrc = A + (size_t)(m0 + sr) * lda + sg * 8;
  const unsigned short* Bsrc = B + (size_t)(n0 + sr) * ldb + sg * 8;
  const size_t a32 = (size_t)32 * lda;
  const size_t b32 = (size_t)32 * ldb;
  const int o0 = tid * 8;
  const int o1 = 2048 + tid * 8;

  f32x4 acc[2][2];
#pragma unroll
  for (int f = 0; f < 2; ++f)
#pragma unroll
    for (int g = 0; g < 2; ++g) acc[f][g] = (f32x4){0.f, 0.f, 0.f, 0.f};

#define STG(kt, buf)                                  \
  do {                                                \
    gload16(Asrc + (kt) * 64, &As[(buf)][o0]);        \
    gload16(Asrc + a32 + (kt) * 64, &As[(buf)][o1]);  \
    gload16(Bsrc + (kt) * 64, &Bs[(buf)][o0]);        \
    gload16(Bsrc + b32 + (kt) * 64, &Bs[(buf)][o1]);  \
  } while (0)

  STG(0, 0);
  STG(1, 1);

#pragma unroll
  for (int t = 0; t < NKT; ++t) {
    if (t < NKT - 1) {
      asm volatile("s_waitcnt vmcnt(4)" ::: "memory");
    } else {
      asm volatile("s_waitcnt vmcnt(0)" ::: "memory");
    }
    __builtin_amdgcn_sched_barrier(0);
    __builtin_amdgcn_s_barrier();
    __builtin_amdgcn_sched_barrier(0);
    if (t + 2 < NKT) STG(t + 2, (t + 2) % 3);
    const int cb = t % 3;
    bf16x8 av[2][2], bv[2][2];
#pragma unroll
    for (int f = 0; f < 2; ++f) {
      const int ra = wr * 32 + f * 16 + l15;
#pragma unroll
      for (int ks = 0; ks < 2; ++ks) {
        const int qa = (ks * 4 + kb + l15) & 7;
        av[f][ks] = *reinterpret_cast<const bf16x8*>(&As[cb][ra * 64 + qa * 8]);
      }
    }
#pragma unroll
    for (int g = 0; g < 2; ++g) {
      const int rb = wc * 32 + g * 16 + l15;
#pragma unroll
      for (int ks = 0; ks < 2; ++ks) {
        const int qb2 = (ks * 4 + kb + l15) & 7;
        bv[g][ks] = *reinterpret_cast<const bf16x8*>(&Bs[cb][rb * 64 + qb2 * 8]);
      }
    }
#pragma unroll
    for (int ks = 0; ks < 2; ++ks)
#pragma unroll
      for (int f = 0; f < 2; ++f)
#pragma unroll
        for (int g = 0; g < 2; ++g)
          acc[f][g] = __builtin_amdgcn_mfma_f32_16x16x32_bf16(av[f][ks], bv[g][ks], acc[f][g], 0, 0, 0);
  }
#undef STG

  // epilogue: C/D col = lane&15, row = (lane>>4)*4 + j
#pragma unroll
  for (int f = 0; f < 2; ++f) {
#pragma unroll
    for (int g = 0; g < 2; ++g) {
#pragma unroll
      for (int j = 0; j < 4; ++j) {
        int m = m0 + wr * 32 + f * 16 + kb * 4 + j;
        int n = n0 + wc * 32 + g * 16 + l15;
        size_t fidx = (size_t)m * 1024 + n;
        size_t cidx = (size_t)m * ldc + n;
        float v = acc[f][g][j];
        if (MODE == 0) {                  // plain bf16 (A1/A2)
          dstbf[cidx] = f2b(v);
        } else if (MODE == 1) {           // h-stage
          float h = v + bias0[n];
          float thv = tanhf(h);
          float r = h + 0.1f * bias1[n];
          dstf0[fidx] = r;
          dstf1[fidx] = thv;
          dstbf[cidx] = f2b(r);
        } else if (MODE == 2) {           // b1v = 11 th + 0.1 c1 -> zcat lo
          dstbf[cidx] = f2b(11.0f * src0[fidx] + 0.1f * v);
        } else if (MODE == 4) {           // r2u; store 0.1*r2u bf16 -> zcat hi
          float r = src0[fidx] + 0.1f * bias0[n] - 0.1f * v;
          dstf0[fidx] = r;
          dstbf[cidx] = f2b(0.1f * r);
        } else if (MODE == 5) {           // b2v = 10 th + v
          dstbf[cidx] = f2b(10.0f * src0[fidx] + v);
        } else if (MODE == 7) {           // y2u = r2u - 0.1 v
          dstbf[cidx] = f2b(src0[fidx] - 0.1f * v);
        } else if (MODE == 8) {           // logits
          dstf0[fidx] = v + bias0[n];
        } else {                          // MODE 9: Q = I/11 - (0.01/121) P
          float q = (m == n ? (1.0f / 11.0f) : 0.0f) - (0.01f / 121.0f) * v;
          unsigned short qq = f2b(q);
          dstbf[cidx] = qq;
          if (dstbf2) dstbf2[(size_t)m * 2048 + n] = qq;  // bcat lo (Q1)
        }
      }
    }
  }
}

__device__ __forceinline__ void map512(int b, int& bx, int& by) {
  bx = ((b & 7) << 2) | ((b >> 3) & 3);  // 0..31
  by = b >> 5;                           // 0..15
}
__device__ __forceinline__ void map256(int r, int& bx, int& by) {
  bx = ((r & 7) << 1) | ((r >> 3) & 1);  // 0..15
  by = (r >> 4) & 15;                    // 0..15
}

// D2: G0 (h-stage, blocks 0..511) + QG (Q1,Q2, blocks 512..1023)
__global__ __launch_bounds__(256) void k_D2(
    const unsigned short* __restrict__ xb, const unsigned short* __restrict__ winb,
    const unsigned short* __restrict__ wtb,
    const float* __restrict__ b_in, const float* __restrict__ b1,
    float* __restrict__ r1u, float* __restrict__ th,
    unsigned short* __restrict__ zb0, unsigned short* __restrict__ qb,
    unsigned short* __restrict__ bcat) {
  __shared__ short As[3][4096];
  __shared__ short Bs[3][4096];
  const int b = blockIdx.x;
  int bx, by;
  if (b < 512) {
    map512(b, bx, by);
    gemm64<1, 16>(xb, 1024, winb, 1024, bx, by, b_in, b1, nullptr,
                  r1u, th, zb0, 1024, nullptr, As, Bs);
  } else {
    int r = b - 512;
    const int z = r >> 8;
    map256(r & 255, bx, by);
    const unsigned short* wt = wtb + (size_t)z * M1;
    gemm64<9, 16>(wt, 1024, wt, 1024, bx, by, nullptr, nullptr, nullptr,
                  nullptr, nullptr, qb + (size_t)z * M1, 1024,
                  z == 0 ? bcat : nullptr, As, Bs);
  }
}

// D3: A1 (0..255), A2 (256..511), G1/b1v (512..1023)
__global__ __launch_bounds__(256) void k_D3(
    const unsigned short* __restrict__ wb, const unsigned short* __restrict__ qb,
    const unsigned short* __restrict__ zb0, const unsigned short* __restrict__ wtb,
    const float* __restrict__ th,
    unsigned short* __restrict__ a1b, unsigned short* __restrict__ a2b,
    unsigned short* __restrict__ zcat) {
  __shared__ short As[3][4096];
  __shared__ short Bs[3][4096];
  const int b = blockIdx.x;
  int bx, by;
  if (b < 512) {
    const int z = b >> 8;
    map256(b & 255, bx, by);
    gemm64<0, 16>(wb + (size_t)z * M1, 1024, qb + (size_t)z * M1, 1024, bx, by,
                  nullptr, nullptr, nullptr, nullptr, nullptr,
                  z == 0 ? a1b : a2b, 1024, nullptr, As, Bs);
  } else {
    map512(b - 512, bx, by);
    gemm64<2, 16>(zb0, 1024, wtb, 1024, bx, by, nullptr, nullptr, th,
                  nullptr, nullptr, zcat, 2048, nullptr, As, Bs);
  }
}

// D4: r2u = r1u + 0.1 b2 - 0.1 NT(b1v, A1)
__global__ __launch_bounds__(256) void k_D4(
    const unsigned short* __restrict__ zcat, const unsigned short* __restrict__ a1b,
    const float* __restrict__ b2, const float* __restrict__ r1u,
    float* __restrict__ r2u, unsigned short* __restrict__ zcat_hi) {
  __shared__ short As[3][4096];
  __shared__ short Bs[3][4096];
  int bx, by;
  map512(blockIdx.x, bx, by);
  gemm64<4, 16>(zcat, 2048, a1b, 1024, bx, by, b2, nullptr, r1u,
                r2u, nullptr, zcat_hi, 2048, nullptr, As, Bs);
}

// D5: b2v = 10 th + [b1v | 0.1 r2u] @ bcat  (K=2048)
__global__ __launch_bounds__(256) void k_D5(
    const unsigned short* __restrict__ zcat, const unsigned short* __restrict__ bcat,
    const float* __restrict__ th, unsigned short* __restrict__ zb2) {
  __shared__ short As[3][4096];
  __shared__ short Bs[3][4096];
  int bx, by;
  map512(blockIdx.x, bx, by);
  gemm64<5, 32>(zcat, 2048, bcat, 2048, bx, by, nullptr, nullptr, th,
                nullptr, nullptr, zb2, 1024, nullptr, As, Bs);
}

// D6: y2u = r2u - 0.1 NT(b2v, A2)
__global__ __launch_bounds__(256) void k_D6(
    const unsigned short* __restrict__ zb2, const unsigned short* __restrict__ a2b,
    const float* __restrict__ r2u, unsigned short* __restrict__ zb3) {
  __shared__ short As[3][4096];
  __shared__ short Bs[3][4096];
  int bx, by;
  map512(blockIdx.x, bx, by);
  gemm64<7, 16>(zb2, 1024, a2b, 1024, bx, by, nullptr, nullptr, r2u,
                nullptr, nullptr, zb3, 1024, nullptr, As, Bs);
}

// D7: logits = NT(y2u, Wout_pad) + bout
__global__ __launch_bounds__(256) void k_D7(
    const unsigned short* __restrict__ zb3, const unsigned short* __restrict__ woutb,
    const float* __restrict__ boutp, float* __restrict__ lgts) {
  __shared__ short As[3][4096];
  __shared__ short Bs[3][4096];
  int bx, by;
  map512(blockIdx.x, bx, by);
  gemm64<8, 16>(zb3, 1024, woutb, 1024, bx, by, boutp, nullptr, nullptr,
                lgts, nullptr, nullptr, 1024, nullptr, As, Bs);
}

// prep: W1/W2 bf16+transpose (0..2047; W2 also fills bcat hi), x (2048..4095),
// W_in (4096..5119), W_out padded (5120..6143), b_out (6144)
__global__ __launch_bounds__(256) void k_prep(
    const float* __restrict__ x, const float* __restrict__ Win,
    const float* __restrict__ W1, const float* __restrict__ W2,
    const float* __restrict__ Wout, const float* __restrict__ bout,
    unsigned short* __restrict__ xb, unsigned short* __restrict__ winb,
    unsigned short* __restrict__ wb, unsigned short* __restrict__ wtb,
    unsigned short* __restrict__ woutb, float* __restrict__ boutp,
    unsigned short* __restrict__ bcat) {
  __shared__ float tile[32][33];
  const int b = blockIdx.x;
  const int tid = threadIdx.x;
  if (b < 2048) {
    const int isW2 = (b >> 10) & 1;
    const float* W = isW2 ? W2 : W1;
    unsigned short* Wb = wb + ((size_t)isW2 << 20);
    unsigned short* WTb = wtb + ((size_t)isW2 << 20);
    const int rem = b & 1023;
    const int tbx = rem & 31, tby = rem >> 5;
    const int tx = tid & 31, ty = tid >> 5;
#pragma unroll
    for (int i = ty; i < 32; i += 8) {
      float v = W[(size_t)(tby * 32 + i) * 1024 + tbx * 32 + tx];
      tile[i][tx] = v;
      Wb[(size_t)(tby * 32 + i) * 1024 + tbx * 32 + tx] = f2b(v);
    }
    __syncthreads();
#pragma unroll
    for (int i = ty; i < 32; i += 8) {
      unsigned short t2 = f2b(tile[tx][i]);
      int rr = tbx * 32 + i, cc = tby * 32 + tx;
      WTb[(size_t)rr * 1024 + cc] = t2;
      if (isW2) bcat[(size_t)rr * 2048 + 1024 + cc] = t2;  // bcat hi = W2^T
    }
  } else if (b < 4096) {
    int i = (b - 2048) * 256 + tid;
    float4 v = ((const float4*)x)[i];
    ((ushort4*)xb)[i] = (ushort4){f2b(v.x), f2b(v.y), f2b(v.z), f2b(v.w)};
  } else if (b < 5120) {
    int i = (b - 4096) * 256 + tid;
    float4 v = ((const float4*)Win)[i];
    ((ushort4*)winb)[i] = (ushort4){f2b(v.x), f2b(v.y), f2b(v.z), f2b(v.w)};
  } else if (b < 6144) {
    int i = (b - 5120) * 256 + tid;
    ushort4 o = (ushort4){0, 0, 0, 0};
    if ((i >> 8) < 1000) {
      float4 v = ((const float4*)Wout)[i];
      o = (ushort4){f2b(v.x), f2b(v.y), f2b(v.z), f2b(v.w)};
    }
    ((ushort4*)woutb)[i] = o;
  } else {
    for (int j = tid; j < 1024; j += 256) boutp[j] = (j < 1000) ? bout[j] : 0.0f;
  }
}

// row softmax over first 1000 cols of 2048x1024 logits -> 2048x1000
__global__ __launch_bounds__(256) void k_softmax(const float* __restrict__ lg,
                                                 float* __restrict__ out) {
  const int r = blockIdx.x;
  const float* p = lg + (size_t)r * 1024;
  float* q = out + (size_t)r * 1000;
  const int tid = threadIdx.x;
  const int lane = tid & 63;
  const int w = tid >> 6;
  __shared__ float redm[4];
  __shared__ float reds[4];
  float m = -3.0e38f;
  for (int i = tid; i < 1000; i += 256) m = fmaxf(m, p[i]);
#pragma unroll
  for (int o = 32; o > 0; o >>= 1) m = fmaxf(m, __shfl_xor(m, o));
  if (lane == 0) redm[w] = m;
  __syncthreads();
  m = fmaxf(fmaxf(redm[0], redm[1]), fmaxf(redm[2], redm[3]));
  float s = 0.0f;
  for (int i = tid; i < 1000; i += 256) {
    float e = __expf(p[i] - m);
    q[i] = e;
    s += e;
  }
#pragma unroll
  for (int o = 32; o > 0; o >>= 1) s += __shfl_xor(s, o);
  if (lane == 0) reds[w] = s;
  __syncthreads();
  float inv = 1.0f / (reds[0] + reds[1] + reds[2] + reds[3]);
  for (int i = tid; i < 1000; i += 256) q[i] *= inv;
}

extern "C" void kernel_launch(void* const* d_in, const int* in_sizes, int n_in,
                              void* d_out, int out_size, void* d_ws, size_t ws_size,
                              hipStream_t stream) {
  const float* x = (const float*)d_in[0];
  const float* W_in = (const float*)d_in[1];
  const float* b_in = (const float*)d_in[2];
  const float* W1 = (const float*)d_in[3];
  const float* b1 = (const float*)d_in[4];
  const float* W2 = (const float*)d_in[5];
  const float* b2 = (const float*)d_in[6];
  const float* W_out = (const float*)d_in[7];
  const float* b_out = (const float*)d_in[8];
  float* out = (float*)d_out;

  const size_t Bm = 2048, U = 1024;
  char* ws = (char*)d_ws;
  size_t off = 0;
  auto alloc = [&](size_t bytes) -> void* {
    void* p = ws + off;
    off += (bytes + 255) & ~(size_t)255;
    return p;
  };
  unsigned short* xb = (unsigned short*)alloc(Bm * U * 2);
  unsigned short* winb = (unsigned short*)alloc((size_t)M1 * 2);
  unsigned short* wb = (unsigned short*)alloc(2 * (size_t)M1 * 2);    // W1,W2
  unsigned short* wtb = (unsigned short*)alloc(2 * (size_t)M1 * 2);   // W1^T,W2^T
  unsigned short* qb = (unsigned short*)alloc(2 * (size_t)M1 * 2);    // Q1,Q2
  unsigned short* a1b = (unsigned short*)alloc((size_t)M1 * 2);       // W1@Q1
  unsigned short* a2b = (unsigned short*)alloc((size_t)M1 * 2);       // W2@Q2
  unsigned short* bcat = (unsigned short*)alloc(2 * (size_t)M1 * 2);  // [Q1 ; W2^T] 1024x2048
  unsigned short* woutb = (unsigned short*)alloc((size_t)M1 * 2);
  float* boutp = (float*)alloc(U * 4);
  unsigned short* zb0 = (unsigned short*)alloc(Bm * U * 2);           // r1u bf16
  unsigned short* zcat = (unsigned short*)alloc(Bm * 2 * U * 2);      // [b1v | 0.1 r2u]
  unsigned short* zb2 = (unsigned short*)alloc(Bm * U * 2);           // b2v
  unsigned short* zb3 = (unsigned short*)alloc(Bm * U * 2);           // y2u
  float* r1u = (float*)alloc(Bm * U * 4);
  float* th = (float*)alloc(Bm * U * 4);
  float* r2u = (float*)alloc(Bm * U * 4);
  float* lgts = (float*)alloc(Bm * U * 4);

  k_prep<<<6145, 256, 0, stream>>>(x, W_in, W1, W2, W_out, b_out,
                                   xb, winb, wb, wtb, woutb, boutp, bcat);
  k_D2<<<1024, 256, 0, stream>>>(xb, winb, wtb, b_in, b1, r1u, th, zb0, qb, bcat);
  k_D3<<<1024, 256, 0, stream>>>(wb, qb, zb0, wtb, th, a1b, a2b, zcat);
  k_D4<<<512, 256, 0, stream>>>(zcat, a1b, b2, r1u, r2u, zcat + 1024);
  k_D5<<<512, 256, 0, stream>>>(zcat, bcat, th, zb2);
  k_D6<<<512, 256, 0, stream>>>(zb2, a2b, r2u, zb3);
  k_D7<<<512, 256, 0, stream>>>(zb3, woutb, boutp, lgts);
  k_softmax<<<2048, 256, 0, stream>>>(lgts, out);
}